// Round 7
// baseline (48.602 us; speedup 1.0000x reference)
//
#include <hip/hip_runtime.h>
#include <hip/hip_bf16.h>

typedef __attribute__((ext_vector_type(8))) short short8_t;
typedef __attribute__((ext_vector_type(4))) float f32x4;

#define BATCH 64
#define L0 16384
#define L1 8192
#define NPG 4096
#define CF 8
#define H 64
#define CHUNK 128
#define NCHUNK 32
#define NCHUNKS_TOTAL (BATCH * NCHUNK)   // 2048

// ---- LDS arena byte offsets ----
// live ranges: w1t ph1-ph5start(load in ph4) | wct ph1-ph2start | x ph1-ph2 |
// t1 ph2-ph3 | nd ph3-ph4 | sa ph4-ph5 | h1 ph5-ph6 | w2t ph1-ph6 | red ph6
#define A_W1T   0        // [4][64][8] ushort = 4096   (dead before h1 write)
#define A_WCT   4096     // [64][8] ushort    = 1024
#define A_X     5120     // [536] f32         = 2144 -> 7264
#define A_T1    7264     // [266][8] ushort   = 4256 -> 11520
#define A_ND    11520    // [132][8] ushort   = 2112 -> 13632 (bf16)
#define A_H1    0        // [130][72] ushort  = 18720 (covers w1t/wct/x/t1/nd, all dead)
#define A_W2T   18720    // [8][64][8] ushort = 8192 -> 26912 (lives until ph6)
#define A_SA    26912    // [130][8] ushort   = 2080 -> 28992
#define A_RED   28992    // [4][64] f32       = 1024 -> 30016
#define ARENA_BYTES 30016

__device__ __forceinline__ float disv(int p) {
    if (p < 0 || p >= NPG) return 0.f;
    if (p == 0 || p == NPG - 1) return 0.70710678118654752f;  // 1/sqrt(2)
    return 0.57735026918962576f;                              // 1/sqrt(3)
}

// packed f32x2 -> bf16x2 (v_cvt_pk_bf16_f32, RNE)
__device__ __forceinline__ unsigned pack_bf2(float a, float b) {
    union { __hip_bfloat162 h2; unsigned u; } cv;
    cv.h2 = __float22bfloat162_rn(make_float2(a, b));
    return cv.u;
}
__device__ __forceinline__ unsigned short bfu(float f) {
    union { __hip_bfloat16 h; unsigned short u; } cv;
    cv.h = __float2bfloat16(f);
    return cv.u;
}
__device__ __forceinline__ float lof(unsigned u) { return __uint_as_float(u << 16); }
__device__ __forceinline__ float hif(unsigned u) { return __uint_as_float(u & 0xffff0000u); }

// Single fused kernel: conv1+pool -> conv2(MFMA)+pool -> GCN1(MFMA, swapped)
// -> GCN2(MFMA) -> mean-pool -> fc -> atomicAdd into out.
__global__ __launch_bounds__(256, 5) void k_fused(const float* __restrict__ x,
        const float* __restrict__ c1w, const float* __restrict__ c1b,
        const float* __restrict__ c2w, const float* __restrict__ c2b,
        const float* __restrict__ g1w, const float* __restrict__ g1b,
        const float* __restrict__ g2w, const float* __restrict__ g2b,
        const float* __restrict__ fcw, const float* __restrict__ fcb,
        float* __restrict__ out) {
    __shared__ __align__(16) char arena[ARENA_BYTES];
    unsigned short* w1t  = (unsigned short*)(arena + A_W1T);
    unsigned short* wct  = (unsigned short*)(arena + A_WCT);
    float*          x_l  = (float*)(arena + A_X);
    unsigned short* t1_l = (unsigned short*)(arena + A_T1);
    unsigned short* nd_l = (unsigned short*)(arena + A_ND);
    unsigned short* h1_l = (unsigned short*)(arena + A_H1);
    unsigned short* w2t  = (unsigned short*)(arena + A_W2T);
    unsigned short* sa_l = (unsigned short*)(arena + A_SA);
    float*          red  = (float*)(arena + A_RED);

    const int tid = threadIdx.x;
    const int wave = tid >> 6;
    const int l = tid & 63;
    const int m = l & 15, q = l >> 4;

    const int chunk = blockIdx.x;
    const int b = chunk >> 5, ch = chunk & 31;
    const int s = ch * CHUNK;
    const bool edgeblk = (ch == 0) || (ch == NCHUNK - 1);

    const f32x4 z4 = {0.f, 0.f, 0.f, 0.f};
    const float T = 1.f / 3.f;

    // ---- phase 1: build frag tables in LDS + stage x ----
    for (int e = tid; e < 4096; e += 256) {          // w2t[ct][ks][lane][i], x1/3
        int i = e & 7, lane = (e >> 3) & 63, ks = (e >> 9) & 1, ct = e >> 10;
        int k = ks * 32 + (lane >> 4) * 8 + i;
        int n = ct * 16 + (lane & 15);
        w2t[e] = bfu(g2w[k * H + n] * T);
    }
    for (int e = tid; e < 2048; e += 256) {          // w1t[ct][lane][i], x1/3
        int i = e & 7, lane = (e >> 3) & 63, ct = e >> 9;
        int k = (lane >> 4) * 8 + i;
        int n = ct * 16 + (lane & 15);
        w1t[e] = (k < CF) ? bfu(g1w[k * H + n] * T) : (unsigned short)0;
    }
    for (int e = tid; e < 512; e += 256) {           // wct[lane][i] (unscaled)
        int i = e & 7, lane = e >> 3;
        int qq = lane >> 4, n = lane & 15;
        wct[e] = (n < CF && qq < 3) ? bfu(c2w[(n * CF + i) * 3 + qq])
                                    : (unsigned short)0;
    }
    {   // x cols [4s-11, 4s+524]
        const float* xb = x + (size_t)b * L0;
        for (int c = tid; c < 536; c += 256) {
            int col = 4 * s - 11 + c;
            x_l[c] = (col >= 0 && col < L0) ? xb[col] : 0.f;
        }
    }
    __syncthreads();

    // ---- phase 2: load wcfr (wct dies) ; conv1+pool -> t1 (bf16, 266 rows) ----
    short8_t wcfr = ((const short8_t*)wct)[l];
    {
        int c0 = (tid & 3) * 2;
        float wA0 = c1w[c0 * 3], wB0 = c1w[c0 * 3 + 1], wC0 = c1w[c0 * 3 + 2];
        float wA1 = c1w[c0 * 3 + 3], wB1 = c1w[c0 * 3 + 4], wC1 = c1w[c0 * 3 + 5];
        float bb0 = c1b[c0], bb1 = c1b[c0 + 1];
        for (int v = tid; v < 266 * 4; v += 256) {
            int t = v >> 2;
            int g = 2 * s - 5 + t;               // global t1 row
            unsigned o = 0;
            if (g >= 0 && g < L1) {
                float a0 = x_l[2 * t], a1 = x_l[2 * t + 1];
                float a2 = x_l[2 * t + 2], a3 = x_l[2 * t + 3];
                float y00 = bb0 + wA0 * a0 + wB0 * a1 + wC0 * a2;
                float y01 = bb0 + wA0 * a1 + wB0 * a2 + wC0 * a3;
                float y10 = bb1 + wA1 * a0 + wB1 * a1 + wC1 * a2;
                float y11 = bb1 + wA1 * a1 + wB1 * a2 + wC1 * a3;
                o = pack_bf2(fmaxf(fmaxf(y00, y01), 0.f),
                             fmaxf(fmaxf(y10, y11), 0.f));
            }
            *(unsigned*)&t1_l[t * 8 + c0] = o;
        }
    }
    __syncthreads();

    // ---- phase 3: conv2 via MFMA (+bias+relu+pool) -> nd (bf16) ----
    {
        float bb2 = (m < CF) ? c2b[m] : 0.f;
        for (int rt = wave; rt < 17; rt += 4) {
            int rr = rt * 16 + m + q;
            rr = rr > 265 ? 265 : rr;            // clamped rows feed only unwritten outputs
            short8_t a = *(const short8_t*)&t1_l[rr * 8];
            f32x4 c = __builtin_amdgcn_mfma_f32_16x16x32_bf16(a, wcfr, z4, 0, 0, 0);
            if (m < CF) {
                int n0 = rt * 8 + q * 2;
                if (n0 < 132)
                    nd_l[n0 * 8 + m] = bfu(fmaxf(fmaxf(c[0], c[1]) + bb2, 0.f));
                if (n0 + 1 < 132)
                    nd_l[(n0 + 1) * 8 + m] = bfu(fmaxf(fmaxf(c[2], c[3]) + bb2, 0.f));
            }
        }
    }
    __syncthreads();

    // ---- phase 4: sa = stencil(nd) (bf16); also preload w1 frags (w1t dies) ----
    short8_t w1fr[4];
    float4 b1v[4];
    #pragma unroll
    for (int ct = 0; ct < 4; ++ct) {
        w1fr[ct] = ((const short8_t*)w1t)[ct * 64 + l];
        b1v[ct] = *(const float4*)&g1b[ct * 16 + q * 4];
    }
    for (int v = tid; v < 260; v += 256) {
        int r = v >> 1, half = v & 1;            // sa row r <-> node s-1+r
        uint2 RL = *(const uint2*)&nd_l[r * 8 + half * 4];
        uint2 RM = *(const uint2*)&nd_l[(r + 1) * 8 + half * 4];
        uint2 RH = *(const uint2*)&nd_l[(r + 2) * 8 + half * 4];
        float o0, o1, o2, o3;
        if (!edgeblk) {
            o0 = lof(RL.x) + lof(RM.x) + lof(RH.x);
            o1 = hif(RL.x) + hif(RM.x) + hif(RH.x);
            o2 = lof(RL.y) + lof(RM.y) + lof(RH.y);
            o3 = hif(RL.y) + hif(RM.y) + hif(RH.y);
        } else {
            int p = s - 1 + r;
            float dc = disv(p);
            float cm_ = 3.f * dc * dc;
            float cl_ = 3.f * dc * disv(p - 1);
            float cr_ = 3.f * dc * disv(p + 1);
            o0 = cm_ * lof(RM.x) + cl_ * lof(RL.x) + cr_ * lof(RH.x);
            o1 = cm_ * hif(RM.x) + cl_ * hif(RL.x) + cr_ * hif(RH.x);
            o2 = cm_ * lof(RM.y) + cl_ * lof(RL.y) + cr_ * lof(RH.y);
            o3 = cm_ * hif(RM.y) + cl_ * hif(RL.y) + cr_ * hif(RH.y);
        }
        *(uint2*)&sa_l[r * 8 + half * 4] = make_uint2(pack_bf2(o0, o1),
                                                      pack_bf2(o2, o3));
    }
    __syncthreads();

    // ---- phase 5: GCN1 MFMA SWAPPED: D = W1^T x sa^T -> lane holds one node's
    //      4 consecutive feats -> b64 writes to row-major h1[node][feat] ----
    for (int rt = wave; rt < 9; rt += 4) {
        int rc = rt * 16 + m;
        int rcc = rc > 129 ? 129 : rc;           // clamped cols -> unwritten nodes
        short8_t sfr = *(const short8_t*)&sa_l[rcc * 8];
        bool wok = rc < 130;
        #pragma unroll
        for (int ct = 0; ct < 4; ++ct) {
            f32x4 c = __builtin_amdgcn_mfma_f32_16x16x32_bf16(w1fr[ct], sfr, z4, 0, 0, 0);
            if (wok) {
                unsigned p01 = pack_bf2(fmaxf(c[0] + b1v[ct].x, 0.f),
                                        fmaxf(c[1] + b1v[ct].y, 0.f));
                unsigned p23 = pack_bf2(fmaxf(c[2] + b1v[ct].z, 0.f),
                                        fmaxf(c[3] + b1v[ct].w, 0.f));
                *(uint2*)&h1_l[rc * 72 + ct * 16 + q * 4] = make_uint2(p01, p23);
            }
        }
    }
    __syncthreads();

    // ---- phase 6: GCN2 MFMA (A2 = 3-row add of h1, 1/3 in W2) + pool ----
    {
        short8_t w2fr[4][2];
        float b2v[4];
        #pragma unroll
        for (int ct = 0; ct < 4; ++ct) {
            w2fr[ct][0] = ((const short8_t*)w2t)[(ct * 2 + 0) * 64 + l];
            w2fr[ct][1] = ((const short8_t*)w2t)[(ct * 2 + 1) * 64 + l];
            b2v[ct] = g2b[ct * 16 + m];
        }
        float pool_acc[4] = {0.f, 0.f, 0.f, 0.f};
        for (int rt = wave; rt < 8; rt += 4) {
            f32x4 accg[4] = {z4, z4, z4, z4};
            int r0 = rt * 16 + m;                // h1 row of p-1
            float cl_ = 0.f, cm_ = 0.f, cr_ = 0.f;
            if (edgeblk) {
                int p = s + r0;                  // output node
                float dcp = disv(p);
                cm_ = 3.f * dcp * dcp;
                cl_ = 3.f * dcp * disv(p - 1);
                cr_ = 3.f * dcp * disv(p + 1);
            }
            #pragma unroll
            for (int ks = 0; ks < 2; ++ks) {
                int koff = ks * 32 + q * 8;
                uint4 lo = *(const uint4*)&h1_l[r0 * 72 + koff];
                uint4 mi = *(const uint4*)&h1_l[(r0 + 1) * 72 + koff];
                uint4 hi = *(const uint4*)&h1_l[(r0 + 2) * 72 + koff];
                union { unsigned u[4]; short8_t s8; } a2;
                #define A2COMP(e, UL, UM, UH)                                     \
                  { float sl, sh;                                                 \
                    if (!edgeblk) {                                               \
                        sl = lof(UL) + lof(UM) + lof(UH);                         \
                        sh = hif(UL) + hif(UM) + hif(UH);                         \
                    } else {                                                      \
                        sl = cm_ * lof(UM) + cl_ * lof(UL) + cr_ * lof(UH);       \
                        sh = cm_ * hif(UM) + cl_ * hif(UL) + cr_ * hif(UH);       \
                    }                                                             \
                    a2.u[e] = pack_bf2(sl, sh); }
                A2COMP(0, lo.x, mi.x, hi.x)
                A2COMP(1, lo.y, mi.y, hi.y)
                A2COMP(2, lo.z, mi.z, hi.z)
                A2COMP(3, lo.w, mi.w, hi.w)
                #undef A2COMP
                #pragma unroll
                for (int ct = 0; ct < 4; ++ct)
                    accg[ct] = __builtin_amdgcn_mfma_f32_16x16x32_bf16(
                        a2.s8, w2fr[ct][ks], accg[ct], 0, 0, 0);
            }
            #pragma unroll
            for (int ct = 0; ct < 4; ++ct)
                #pragma unroll
                for (int i = 0; i < 4; ++i)
                    pool_acc[ct] += fmaxf(accg[ct][i] + b2v[ct], 0.f);
        }
        #pragma unroll
        for (int ct = 0; ct < 4; ++ct) {
            float v = pool_acc[ct];
            v += __shfl_xor(v, 16);
            v += __shfl_xor(v, 32);
            if (q == 0) red[wave * 64 + ct * 16 + m] = v;
        }
    }
    __syncthreads();

    // ---- mean-pool x fc -> atomicAdd 2 floats per block ----
    if (tid < H) {
        float v = red[tid] + red[64 + tid] + red[128 + tid] + red[192 + tid];
        float s0 = v * fcw[tid * 2 + 0];
        float s1 = v * fcw[tid * 2 + 1];
        #pragma unroll
        for (int o = 32; o; o >>= 1) {
            s0 += __shfl_down(s0, o);
            s1 += __shfl_down(s1, o);
        }
        if (tid == 0) {
            atomicAdd(&out[b * 2 + 0], s0 * (1.f / NPG));
            atomicAdd(&out[b * 2 + 1], s1 * (1.f / NPG));
            if (ch == 0) {
                atomicAdd(&out[b * 2 + 0], fcb[0]);
                atomicAdd(&out[b * 2 + 1], fcb[1]);
            }
        }
    }
}

extern "C" void kernel_launch(void* const* d_in, const int* in_sizes, int n_in,
                              void* d_out, int out_size, void* d_ws, size_t ws_size,
                              hipStream_t stream) {
    (void)in_sizes; (void)n_in; (void)d_ws; (void)ws_size;
    const float* x   = (const float*)d_in[0];
    const float* c1w = (const float*)d_in[2];
    const float* c1b = (const float*)d_in[3];
    const float* c2w = (const float*)d_in[4];
    const float* c2b = (const float*)d_in[5];
    const float* g1w = (const float*)d_in[6];
    const float* g1b = (const float*)d_in[7];
    const float* g2w = (const float*)d_in[8];
    const float* g2b = (const float*)d_in[9];
    const float* fcw = (const float*)d_in[10];
    const float* fcb = (const float*)d_in[11];
    float* out = (float*)d_out;

    hipMemsetAsync(out, 0, (size_t)out_size * sizeof(float), stream);
    k_fused<<<NCHUNKS_TOTAL, 256, 0, stream>>>(x, c1w, c1b, c2w, c2b,
                                               g1w, g1b, g2w, g2b, fcw, fcb, out);
}